// Round 1
// baseline (483.970 us; speedup 1.0000x reference)
//
#include <hip/hip_runtime.h>
#include <hip/hip_bf16.h>
#include <math.h>

#define TN 201
#define NSTEP 200
#define BATCH 4096
#define DIM 20
#define HID 128

typedef __attribute__((ext_vector_type(8))) short short8;
typedef __attribute__((ext_vector_type(4))) float f32x4;

union S8U { short8 s; unsigned u[4]; };

__device__ __forceinline__ unsigned pk2(float lo, float hi) {
  __hip_bfloat162 h = __float22bfloat162_rn(make_float2(lo, hi));
  union { __hip_bfloat162 h; unsigned u; } v;
  v.h = h;
  return v.u;
}
__device__ __forceinline__ float tanh_fast(float x) {
  float e = __builtin_amdgcn_exp2f(x * 2.8853900817779268f);
  return 1.f - 2.f * __builtin_amdgcn_rcpf(e + 1.f);
}

// ws layout (floats):
//   [0..399]     Pp  = sigma^T P
//   [400..799]   Mp  = -sigma^T A sigma^{-T}
//   [800..1199]  Qp  = sigma^T Q
//   [1200..1399] dt[200]
//   [1400..1599] 1/sqrt(dt)[200]
//   [1600..1631] b2p = sigma^T b2 (padded to 32, zeros beyond 20)
//   [2048..4607] W2p = W2 sigma  [128][20]
//   [8192 ...]   zc: A1[nch][81920], A2[nch][81920], S[nch][81920]

// ================= k0: setup =================
__global__ __launch_bounds__(256) void k0_setup(
    const float* __restrict__ ts, const float* __restrict__ sigma,
    const float* __restrict__ A, const float* __restrict__ P,
    const float* __restrict__ Q, const float* __restrict__ W2,
    const float* __restrict__ b2, float* __restrict__ wsc) {
  __shared__ float aug[20][40];
  __shared__ float sS[400], sA[400], sT1[400];
  __shared__ float fac[20];
  __shared__ float piv;
  int tid = threadIdx.x;
  for (int e = tid; e < 400; e += 256) { sS[e] = sigma[e]; sA[e] = A[e]; }
  for (int e = tid; e < 800; e += 256) {
    int i = e / 40, j = e % 40;
    aug[i][j] = (j < 20) ? sigma[i * 20 + j] : ((j - 20) == i ? 1.f : 0.f);
  }
  __syncthreads();
  for (int p = 0; p < 20; ++p) {
    if (tid == 0) piv = 1.f / aug[p][p];
    __syncthreads();
    if (tid < 40) aug[p][tid] *= piv;
    __syncthreads();
    if (tid < 20) fac[tid] = aug[tid][p];
    __syncthreads();
    for (int e = tid; e < 800; e += 256) {
      int i = e / 40, j = e % 40;
      if (i != p) aug[i][j] -= fac[i] * aug[p][j];
    }
    __syncthreads();
  }
  // T1[k][j] = (A sigma^{-T})[k][j]
  for (int e = tid; e < 400; e += 256) {
    int k = e / 20, j = e % 20;
    float s = 0.f;
    for (int l2 = 0; l2 < 20; ++l2) s += sA[k * 20 + l2] * aug[j][20 + l2];
    sT1[e] = s;
  }
  __syncthreads();
  for (int e = tid; e < 400; e += 256) {
    int i = e / 20, j = e % 20;
    float m = 0.f, pp = 0.f, qq = 0.f;
    for (int k = 0; k < 20; ++k) {
      float sk = sS[k * 20 + i];
      m += sk * sT1[k * 20 + j];
      pp += sk * P[k * 20 + j];
      qq += sk * Q[k * 20 + j];
    }
    wsc[e] = pp;
    wsc[400 + e] = -m;
    wsc[800 + e] = qq;
  }
  for (int e = tid; e < 2560; e += 256) {
    int h = e / 20, i = e % 20;
    float s = 0.f;
    for (int j = 0; j < 20; ++j) s += W2[h * 20 + j] * sS[j * 20 + i];
    wsc[2048 + e] = s;
  }
  if (tid < 32) {
    float s = 0.f;
    if (tid < 20)
      for (int j = 0; j < 20; ++j) s += b2[j] * sS[j * 20 + tid];
    wsc[1600 + tid] = s;
  }
  if (tid < NSTEP) {
    float d = ts[tid + 1] - ts[tid];
    wsc[1200 + tid] = d;
    wsc[1400 + tid] = rsqrtf(d);
  }
}

// ================= kernel A: fused MLP + integrand + chunk scan =================
// per-wave LDS rows: tx pitch 26 (cols: [t, x0..x19, 0 x5]), xy pitch 42
// ([x0..x19, y0..y19, pad2]), H pitch 34 (32 cols). 1632 dw/wave.
#define TXP 26
#define XYP 42
#define HP 34
#define WLDS 1632

#define MFMA16(a, b, c) __builtin_amdgcn_mfma_f32_16x16x32_bf16((a), (b), (c), 0, 0, 0)

__global__ __launch_bounds__(256, 4) void kA(
    const float* __restrict__ states, const float* __restrict__ noises,
    const float* __restrict__ controls, const float* __restrict__ ts,
    const float* __restrict__ W1, const float* __restrict__ b1,
    const float* __restrict__ wsc, float* __restrict__ zc,
    int nch, int cbase, int crem) {
  __shared__ float lds[4 * WLDS];
  const int tid = threadIdx.x;
  const int l = tid & 63;
  const int w = tid >> 6;
  const int quad = l >> 4;
  const int m16 = l & 15;

  const int c = blockIdx.x >> 6;    // 0..nch-1 (chunk; c=0 = highest t)
  const int slab = blockIdx.x & 63; // 0..63
  const int b0 = slab * 64 + w * 16;
  const int sz = cbase + ((c < crem) ? 1 : 0);
  const int thi = 200 - (c * cbase + ((c < crem) ? c : crem));
  const int tlo = thi - (sz - 1);

  const int twx = w * WLDS;
  const int xyb = twx + 16 * TXP;
  const int hb = xyb + 16 * XYP;

  // ---- zero tx pad cols 21..25 (16 rows x 5) ----
  for (int e = l; e < 80; e += 64) lds[twx + (e / 5) * TXP + 21 + e % 5] = 0.f;

  // ---- prologue: gather weight fragments into VGPRs ----
  short8 W1f[8];
#pragma unroll
  for (int nt = 0; nt < 8; ++nt) {
    S8U f;
    int n = nt * 16 + m16;
#pragma unroll
    for (int jj = 0; jj < 4; ++jj) {
      int k0 = quad * 8 + 2 * jj;
      float f0 = (k0 < 21) ? W1[k0 * HID + n] : 0.f;
      float f1 = (k0 + 1 < 21) ? W1[(k0 + 1) * HID + n] : 0.f;
      f.u[jj] = pk2(f0, f1);
    }
    W1f[nt] = f.s;
  }
  short8 W2f[4][2];
#pragma unroll
  for (int p = 0; p < 4; ++p)
#pragma unroll
    for (int nt2 = 0; nt2 < 2; ++nt2) {
      S8U f;
      int n = nt2 * 16 + m16;
      bool ok = (n < 20);
#pragma unroll
      for (int jj = 0; jj < 4; ++jj) {
        int k0 = p * 32 + quad * 8 + 2 * jj;
        float f0 = ok ? wsc[2048 + k0 * 20 + n] : 0.f;
        float f1 = ok ? wsc[2048 + (k0 + 1) * 20 + n] : 0.f;
        f.u[jj] = pk2(f0, f1);
      }
      W2f[p][nt2] = f.s;
    }
  short8 Bs[2][2];
#pragma unroll
  for (int nt2 = 0; nt2 < 2; ++nt2) {
    int n = nt2 * 16 + m16;
    bool ok = (n < 20);
    S8U f0v, f1v;
#pragma unroll
    for (int jj = 0; jj < 4; ++jj) {
      float v0 = 0.f, v1 = 0.f;
      int k0 = quad * 8 + 2 * jj;
      if (ok) {
        v0 = (k0 < 20) ? wsc[n * 20 + k0] : wsc[400 + n * 20 + (k0 - 20)];
        v1 = (k0 + 1 < 20) ? wsc[n * 20 + k0 + 1] : wsc[400 + n * 20 + (k0 + 1 - 20)];
      }
      f0v.u[jj] = pk2(v0, v1);
      float w0 = 0.f, w1 = 0.f;
      if (ok && quad == 0) {
        w0 = wsc[400 + n * 20 + 12 + 2 * jj];
        w1 = wsc[400 + n * 20 + 13 + 2 * jj];
      }
      f1v.u[jj] = pk2(w0, w1);
    }
    Bs[0][nt2] = f0v.s;
    Bs[1][nt2] = f1v.s;
  }
  float b1v[8];
#pragma unroll
  for (int nt = 0; nt < 8; ++nt) b1v[nt] = b1[nt * 16 + m16];
  const float b2pv0 = wsc[1600 + m16];
  const float b2pv1 = wsc[1616 + m16];

  // ---- invariant addresses ----
  int srowA[5], srowX[5];
#pragma unroll
  for (int it = 0; it < 5; ++it) {
    int idx = it * 64 + l;
    int row = idx / 20, col = idx - row * 20;
    srowA[it] = twx + row * TXP + 1 + col;
    srowX[it] = xyb + row * XYP + col;
  }
  const int rdTX = twx + m16 * TXP + quad * 8;
  const int rdXY = xyb + m16 * XYP + quad * 8;
  const int rdXY1 = xyb + m16 * XYP + 32;
  const int wrH = hb + quad * 4 * HP + m16;
  const int rdH = hb + m16 * HP + quad * 8;

  // ---- scan accumulators (C-layout) ----
  f32x4 A1a = {0.f, 0.f, 0.f, 0.f}, A1b = {0.f, 0.f, 0.f, 0.f};
  f32x4 A2a = {0.f, 0.f, 0.f, 0.f}, A2b = {0.f, 0.f, 0.f, 0.f};
  f32x4 La = {0.f, 0.f, 0.f, 0.f}, Lb = {0.f, 0.f, 0.f, 0.f};

  // ---- preload first t ----
  float xv[5], nv[5], cv[5];
  {
    size_t rb = ((size_t)thi * BATCH + b0) * 20;
#pragma unroll
    for (int it = 0; it < 5; ++it) {
      int idx = it * 64 + l;
      xv[it] = states[rb + idx];
      if (thi < 200) {
        nv[it] = noises[rb + idx];
        cv[it] = controls[rb + idx];
      }
    }
  }

#pragma unroll 1
  for (int t = thi; t >= tlo; --t) {
    // prefetch next t (t-1 <= 199 always, so noises/controls valid)
    float xn[5], nn[5], cn[5];
    if (t > tlo) {
      size_t rb = ((size_t)(t - 1) * BATCH + b0) * 20;
#pragma unroll
      for (int it = 0; it < 5; ++it) {
        int idx = it * 64 + l;
        xn[it] = states[rb + idx];
        nn[it] = noises[rb + idx];
        cn[it] = controls[rb + idx];
      }
    }
    const float tval = ts[t];
    const bool has_s = (t < 200);
    const float dtv = has_s ? wsc[1200 + t] : 0.f;
    const float rsd = has_s ? wsc[1400 + t] : 0.f;

    // ---- stage rows to LDS ----
#pragma unroll
    for (int it = 0; it < 5; ++it) {
      lds[srowA[it]] = xv[it];
      lds[srowX[it]] = xv[it];
      if (has_s) lds[srowX[it] + 20] = nv[it] * rsd + cv[it];
    }
    if (l < 16) lds[twx + l * TXP] = tval;

    // ---- XA fragment ----
    S8U af;
    if (quad < 3) {
#pragma unroll
      for (int jj = 0; jj < 4; ++jj) {
        float2 v = *(float2*)&lds[rdTX + 2 * jj];
        af.u[jj] = pk2(v.x, v.y);
      }
    } else {
      af.u[0] = af.u[1] = af.u[2] = af.u[3] = 0u;
    }

    // ---- MLP: layer1 -> tanh -> layer2 ----
    f32x4 u0 = {b2pv0, b2pv0, b2pv0, b2pv0};
    f32x4 u1 = {b2pv1, b2pv1, b2pv1, b2pv1};
#pragma unroll
    for (int p = 0; p < 4; ++p) {
      f32x4 aA = {b1v[2 * p], b1v[2 * p], b1v[2 * p], b1v[2 * p]};
      aA = MFMA16(af.s, W1f[2 * p], aA);
      f32x4 aB = {b1v[2 * p + 1], b1v[2 * p + 1], b1v[2 * p + 1], b1v[2 * p + 1]};
      aB = MFMA16(af.s, W1f[2 * p + 1], aB);
#pragma unroll
      for (int reg = 0; reg < 4; ++reg) {
        lds[wrH + reg * HP] = tanh_fast(aA[reg]);
        lds[wrH + reg * HP + 16] = tanh_fast(aB[reg]);
      }
      S8U hf;
#pragma unroll
      for (int jj = 0; jj < 4; ++jj) {
        float2 v = *(float2*)&lds[rdH + 2 * jj];
        hf.u[jj] = pk2(v.x, v.y);
      }
      u0 = MFMA16(hf.s, W2f[p][0], u0);
      u1 = MFMA16(hf.s, W2f[p][1], u1);
    }

    // ---- integrand s~ (K=40: [x | y]) ----
    f32x4 s0 = {0.f, 0.f, 0.f, 0.f}, s1 = {0.f, 0.f, 0.f, 0.f};
    if (has_s) {
      S8U sf0, sf1;
#pragma unroll
      for (int jj = 0; jj < 4; ++jj) {
        float2 v = *(float2*)&lds[rdXY + 2 * jj];
        sf0.u[jj] = pk2(v.x, v.y);
      }
      if (quad == 0) {
#pragma unroll
        for (int jj = 0; jj < 4; ++jj) {
          float2 v = *(float2*)&lds[rdXY1 + 2 * jj];
          sf1.u[jj] = pk2(v.x, v.y);
        }
      } else {
        sf1.u[0] = sf1.u[1] = sf1.u[2] = sf1.u[3] = 0u;
      }
      f32x4 a0 = {0.f, 0.f, 0.f, 0.f};
      f32x4 a1 = {0.f, 0.f, 0.f, 0.f};
      a0 = MFMA16(sf0.s, Bs[0][0], a0);
      a0 = MFMA16(sf1.s, Bs[1][0], a0);
      a1 = MFMA16(sf0.s, Bs[0][1], a1);
      a1 = MFMA16(sf1.s, Bs[1][1], a1);
      s0 = a0 * dtv;
      s1 = a1 * dtv;
    }

    // ---- scan update ----
    La += s0;
    Lb += s1;
    f32x4 p0 = u0 - La;
    f32x4 p1 = u1 - Lb;
    A2a += p0;
    A2b += p1;
    A1a += p0 * p0;
    A1b += p1 * p1;

    // rotate prefetch
#pragma unroll
    for (int it = 0; it < 5; ++it) {
      xv[it] = xn[it];
      nv[it] = nn[it];
      cv[it] = cn[it];
    }
  }

  // ---- epilogue stores ----
  const size_t CH = (size_t)BATCH * DIM;
  float* zA1 = zc;
  float* zA2 = zc + (size_t)nch * CH;
  float* zS = zc + (size_t)2 * nch * CH;
  const int bb = b0 + quad * 4;
#pragma unroll
  for (int reg = 0; reg < 4; ++reg) {
    size_t base = ((size_t)c * BATCH + (bb + reg)) * 20;
    zA1[base + m16] = A1a[reg];
    zA2[base + m16] = A2a[reg];
    zS[base + m16] = La[reg];
    if (m16 < 4) {
      zA1[base + 16 + m16] = A1b[reg];
      zA2[base + 16 + m16] = A2b[reg];
      zS[base + 16 + m16] = Lb[reg];
    }
  }
}

// ================= kernel B: combine chunks =================
__global__ __launch_bounds__(256) void kB(
    const float* __restrict__ states, const float* __restrict__ lw,
    const float* __restrict__ wsc, const float* __restrict__ zc,
    float* __restrict__ out, int nch, int cbase, int crem) {
  __shared__ float sQp[400];
  int tid = threadIdx.x;
  for (int e = tid; e < 400; e += 256) sQp[e] = wsc[800 + e];
  __syncthreads();
  const int u = blockIdx.x * 256 + tid;  // < 81920
  const int b = u / 20;
  const int i = u - b * 20;
  const float* xp = states + ((size_t)NSTEP * BATCH + b) * 20;
  float term = 0.f;
#pragma unroll
  for (int j = 0; j < 20; ++j) term = fmaf(sQp[i * 20 + j], xp[j], term);

  const size_t CH = (size_t)BATCH * DIM;  // 81920
  float T = 0.f, obj = 0.f;
  for (int c = 0; c < nch; ++c) {
    float A1 = zc[(size_t)c * CH + u];
    float A2 = zc[(size_t)(nch + c) * CH + u];
    float S = zc[(size_t)(2 * nch + c) * CH + u];
    float K = term + T;
    float nc = (float)(cbase + ((c < crem) ? 1 : 0));
    obj += A1 - 2.f * K * A2 + nc * K * K;
    T += S;
  }
  obj *= __expf(lw[b]) * (1.f / ((float)TN * (float)BATCH));
#pragma unroll
  for (int off = 32; off > 0; off >>= 1) obj += __shfl_down(obj, off, 64);
  if ((tid & 63) == 0) atomicAdd(out, obj);
}

extern "C" void kernel_launch(void* const* d_in, const int* in_sizes, int n_in,
                              void* d_out, int out_size, void* d_ws, size_t ws_size,
                              hipStream_t stream) {
  const float* states = (const float*)d_in[0];
  const float* noises = (const float*)d_in[1];
  const float* controls = (const float*)d_in[2];
  const float* lw = (const float*)d_in[3];
  const float* ts = (const float*)d_in[4];
  const float* sigma = (const float*)d_in[5];
  const float* P = (const float*)d_in[6];
  const float* A = (const float*)d_in[7];
  const float* Q = (const float*)d_in[8];
  const float* W1 = (const float*)d_in[9];
  const float* b1 = (const float*)d_in[10];
  const float* W2 = (const float*)d_in[11];
  const float* b2 = (const float*)d_in[12];
  float* out = (float*)d_out;

  float* wsc = (float*)d_ws;
  float* zc = wsc + 8192;

  // choose chunk count by available workspace: nch=16 -> 4 blocks/CU occupancy
  int nch = 16;
  size_t need = ((size_t)8192 + (size_t)3 * nch * BATCH * DIM) * sizeof(float);
  if (ws_size < need) nch = 8;
  int cbase = TN / nch;
  int crem = TN - cbase * nch;

  hipMemsetAsync(out, 0, sizeof(float), stream);
  hipLaunchKernelGGL(k0_setup, dim3(1), dim3(256), 0, stream,
                     ts, sigma, A, P, Q, W2, b2, wsc);
  hipLaunchKernelGGL(kA, dim3(nch * 64), dim3(256), 0, stream,
                     states, noises, controls, ts, W1, b1, wsc, zc, nch, cbase, crem);
  hipLaunchKernelGGL(kB, dim3((BATCH * DIM) / 256), dim3(256), 0, stream,
                     states, lw, wsc, zc, out, nch, cbase, crem);
}

// Round 2
// 315.388 us; speedup vs baseline: 1.5345x; 1.5345x over previous
//
#include <hip/hip_runtime.h>
#include <hip/hip_bf16.h>
#include <math.h>

#define TN 201
#define NSTEP 200
#define BATCH 4096
#define DIM 20
#define HID 128

typedef __attribute__((ext_vector_type(8))) short short8;
typedef __attribute__((ext_vector_type(4))) float f32x4;

union S8U { short8 s; unsigned u[4]; };

__device__ __forceinline__ unsigned pk2(float lo, float hi) {
  __hip_bfloat162 h = __float22bfloat162_rn(make_float2(lo, hi));
  union { __hip_bfloat162 h; unsigned u; } v;
  v.h = h;
  return v.u;
}
__device__ __forceinline__ float tanh_fast(float x) {
  float e = __builtin_amdgcn_exp2f(x * 2.8853900817779268f);
  return 1.f - 2.f * __builtin_amdgcn_rcpf(e + 1.f);
}

// ws layout (floats):
//   [0..399]     Pp  = sigma^T P
//   [400..799]   Mp  = -sigma^T A sigma^{-T}
//   [800..1199]  Qp  = sigma^T Q
//   [1200..1399] dt[200]
//   [1400..1599] 1/sqrt(dt)[200]
//   [1600..1631] b2p = sigma^T b2 (padded to 32, zeros beyond 20)
//   [2048..4607] W2p = W2 sigma  [128][20]
//   [8192 ...]   zc: A1[nch][81920], A2[nch][81920], S[nch][81920]

// ================= k0: setup =================
__global__ __launch_bounds__(256) void k0_setup(
    const float* __restrict__ ts, const float* __restrict__ sigma,
    const float* __restrict__ A, const float* __restrict__ P,
    const float* __restrict__ Q, const float* __restrict__ W2,
    const float* __restrict__ b2, float* __restrict__ wsc) {
  __shared__ float aug[20][40];
  __shared__ float sS[400], sA[400], sT1[400];
  __shared__ float fac[20];
  __shared__ float piv;
  int tid = threadIdx.x;
  for (int e = tid; e < 400; e += 256) { sS[e] = sigma[e]; sA[e] = A[e]; }
  for (int e = tid; e < 800; e += 256) {
    int i = e / 40, j = e % 40;
    aug[i][j] = (j < 20) ? sigma[i * 20 + j] : ((j - 20) == i ? 1.f : 0.f);
  }
  __syncthreads();
  for (int p = 0; p < 20; ++p) {
    if (tid == 0) piv = 1.f / aug[p][p];
    __syncthreads();
    if (tid < 40) aug[p][tid] *= piv;
    __syncthreads();
    if (tid < 20) fac[tid] = aug[tid][p];
    __syncthreads();
    for (int e = tid; e < 800; e += 256) {
      int i = e / 40, j = e % 40;
      if (i != p) aug[i][j] -= fac[i] * aug[p][j];
    }
    __syncthreads();
  }
  // T1[k][j] = (A sigma^{-T})[k][j]
  for (int e = tid; e < 400; e += 256) {
    int k = e / 20, j = e % 20;
    float s = 0.f;
    for (int l2 = 0; l2 < 20; ++l2) s += sA[k * 20 + l2] * aug[j][20 + l2];
    sT1[e] = s;
  }
  __syncthreads();
  for (int e = tid; e < 400; e += 256) {
    int i = e / 20, j = e % 20;
    float m = 0.f, pp = 0.f, qq = 0.f;
    for (int k = 0; k < 20; ++k) {
      float sk = sS[k * 20 + i];
      m += sk * sT1[k * 20 + j];
      pp += sk * P[k * 20 + j];
      qq += sk * Q[k * 20 + j];
    }
    wsc[e] = pp;
    wsc[400 + e] = -m;
    wsc[800 + e] = qq;
  }
  for (int e = tid; e < 2560; e += 256) {
    int h = e / 20, i = e % 20;
    float s = 0.f;
    for (int j = 0; j < 20; ++j) s += W2[h * 20 + j] * sS[j * 20 + i];
    wsc[2048 + e] = s;
  }
  if (tid < 32) {
    float s = 0.f;
    if (tid < 20)
      for (int j = 0; j < 20; ++j) s += b2[j] * sS[j * 20 + tid];
    wsc[1600 + tid] = s;
  }
  if (tid < NSTEP) {
    float d = ts[tid + 1] - ts[tid];
    wsc[1200 + tid] = d;
    wsc[1400 + tid] = rsqrtf(d);
  }
}

// ================= kernel A: fused MLP + integrand + chunk scan =================
// per-wave LDS rows: tx pitch 26 (cols: [t, x0..x19, 0 x5]), xy pitch 42
// ([x0..x19, y0..y19, pad2]), H pitch 34 (32 cols). 1632 dw/wave.
#define TXP 26
#define XYP 42
#define HP 34
#define WLDS 1632

#define MFMA16(a, b, c) __builtin_amdgcn_mfma_f32_16x16x32_bf16((a), (b), (c), 0, 0, 0)

// NOTE: (256,2) is the min-waves GUARANTEE for the allocator, not a cap.
// At the resulting VGPR=108 (<=128) the HW can still co-schedule 4 blocks/CU;
// the nch=16 grid (1024 blocks) supplies them. (256,4) forced VGPR=64 and
// spilled the 20 short8 weight fragments to scratch: FETCH 96->720 MB. Never again.
__global__ __launch_bounds__(256, 2) void kA(
    const float* __restrict__ states, const float* __restrict__ noises,
    const float* __restrict__ controls, const float* __restrict__ ts,
    const float* __restrict__ W1, const float* __restrict__ b1,
    const float* __restrict__ wsc, float* __restrict__ zc,
    int nch, int cbase, int crem) {
  __shared__ float lds[4 * WLDS];
  const int tid = threadIdx.x;
  const int l = tid & 63;
  const int w = tid >> 6;
  const int quad = l >> 4;
  const int m16 = l & 15;

  const int c = blockIdx.x >> 6;    // 0..nch-1 (chunk; c=0 = highest t)
  const int slab = blockIdx.x & 63; // 0..63
  const int b0 = slab * 64 + w * 16;
  const int sz = cbase + ((c < crem) ? 1 : 0);
  const int thi = 200 - (c * cbase + ((c < crem) ? c : crem));
  const int tlo = thi - (sz - 1);

  const int twx = w * WLDS;
  const int xyb = twx + 16 * TXP;
  const int hb = xyb + 16 * XYP;

  // ---- zero tx pad cols 21..25 (16 rows x 5) ----
  for (int e = l; e < 80; e += 64) lds[twx + (e / 5) * TXP + 21 + e % 5] = 0.f;

  // ---- prologue: gather weight fragments into VGPRs ----
  short8 W1f[8];
#pragma unroll
  for (int nt = 0; nt < 8; ++nt) {
    S8U f;
    int n = nt * 16 + m16;
#pragma unroll
    for (int jj = 0; jj < 4; ++jj) {
      int k0 = quad * 8 + 2 * jj;
      float f0 = (k0 < 21) ? W1[k0 * HID + n] : 0.f;
      float f1 = (k0 + 1 < 21) ? W1[(k0 + 1) * HID + n] : 0.f;
      f.u[jj] = pk2(f0, f1);
    }
    W1f[nt] = f.s;
  }
  short8 W2f[4][2];
#pragma unroll
  for (int p = 0; p < 4; ++p)
#pragma unroll
    for (int nt2 = 0; nt2 < 2; ++nt2) {
      S8U f;
      int n = nt2 * 16 + m16;
      bool ok = (n < 20);
#pragma unroll
      for (int jj = 0; jj < 4; ++jj) {
        int k0 = p * 32 + quad * 8 + 2 * jj;
        float f0 = ok ? wsc[2048 + k0 * 20 + n] : 0.f;
        float f1 = ok ? wsc[2048 + (k0 + 1) * 20 + n] : 0.f;
        f.u[jj] = pk2(f0, f1);
      }
      W2f[p][nt2] = f.s;
    }
  short8 Bs[2][2];
#pragma unroll
  for (int nt2 = 0; nt2 < 2; ++nt2) {
    int n = nt2 * 16 + m16;
    bool ok = (n < 20);
    S8U f0v, f1v;
#pragma unroll
    for (int jj = 0; jj < 4; ++jj) {
      float v0 = 0.f, v1 = 0.f;
      int k0 = quad * 8 + 2 * jj;
      if (ok) {
        v0 = (k0 < 20) ? wsc[n * 20 + k0] : wsc[400 + n * 20 + (k0 - 20)];
        v1 = (k0 + 1 < 20) ? wsc[n * 20 + k0 + 1] : wsc[400 + n * 20 + (k0 + 1 - 20)];
      }
      f0v.u[jj] = pk2(v0, v1);
      float w0 = 0.f, w1 = 0.f;
      if (ok && quad == 0) {
        w0 = wsc[400 + n * 20 + 12 + 2 * jj];
        w1 = wsc[400 + n * 20 + 13 + 2 * jj];
      }
      f1v.u[jj] = pk2(w0, w1);
    }
    Bs[0][nt2] = f0v.s;
    Bs[1][nt2] = f1v.s;
  }
  float b1v[8];
#pragma unroll
  for (int nt = 0; nt < 8; ++nt) b1v[nt] = b1[nt * 16 + m16];
  const float b2pv0 = wsc[1600 + m16];
  const float b2pv1 = wsc[1616 + m16];

  // ---- invariant addresses ----
  int srowA[5], srowX[5];
#pragma unroll
  for (int it = 0; it < 5; ++it) {
    int idx = it * 64 + l;
    int row = idx / 20, col = idx - row * 20;
    srowA[it] = twx + row * TXP + 1 + col;
    srowX[it] = xyb + row * XYP + col;
  }
  const int rdTX = twx + m16 * TXP + quad * 8;
  const int rdXY = xyb + m16 * XYP + quad * 8;
  const int rdXY1 = xyb + m16 * XYP + 32;
  const int wrH = hb + quad * 4 * HP + m16;
  const int rdH = hb + m16 * HP + quad * 8;

  // ---- scan accumulators (C-layout) ----
  f32x4 A1a = {0.f, 0.f, 0.f, 0.f}, A1b = {0.f, 0.f, 0.f, 0.f};
  f32x4 A2a = {0.f, 0.f, 0.f, 0.f}, A2b = {0.f, 0.f, 0.f, 0.f};
  f32x4 La = {0.f, 0.f, 0.f, 0.f}, Lb = {0.f, 0.f, 0.f, 0.f};

  // ---- preload first t ----
  float xv[5], nv[5], cv[5];
  {
    size_t rb = ((size_t)thi * BATCH + b0) * 20;
#pragma unroll
    for (int it = 0; it < 5; ++it) {
      int idx = it * 64 + l;
      xv[it] = states[rb + idx];
      if (thi < 200) {
        nv[it] = noises[rb + idx];
        cv[it] = controls[rb + idx];
      }
    }
  }

#pragma unroll 1
  for (int t = thi; t >= tlo; --t) {
    // prefetch next t (t-1 <= 199 always, so noises/controls valid)
    float xn[5], nn[5], cn[5];
    if (t > tlo) {
      size_t rb = ((size_t)(t - 1) * BATCH + b0) * 20;
#pragma unroll
      for (int it = 0; it < 5; ++it) {
        int idx = it * 64 + l;
        xn[it] = states[rb + idx];
        nn[it] = noises[rb + idx];
        cn[it] = controls[rb + idx];
      }
    }
    const float tval = ts[t];
    const bool has_s = (t < 200);
    const float dtv = has_s ? wsc[1200 + t] : 0.f;
    const float rsd = has_s ? wsc[1400 + t] : 0.f;

    // ---- stage rows to LDS ----
#pragma unroll
    for (int it = 0; it < 5; ++it) {
      lds[srowA[it]] = xv[it];
      lds[srowX[it]] = xv[it];
      if (has_s) lds[srowX[it] + 20] = nv[it] * rsd + cv[it];
    }
    if (l < 16) lds[twx + l * TXP] = tval;

    // ---- XA fragment ----
    S8U af;
    if (quad < 3) {
#pragma unroll
      for (int jj = 0; jj < 4; ++jj) {
        float2 v = *(float2*)&lds[rdTX + 2 * jj];
        af.u[jj] = pk2(v.x, v.y);
      }
    } else {
      af.u[0] = af.u[1] = af.u[2] = af.u[3] = 0u;
    }

    // ---- MLP: layer1 -> tanh -> layer2 ----
    f32x4 u0 = {b2pv0, b2pv0, b2pv0, b2pv0};
    f32x4 u1 = {b2pv1, b2pv1, b2pv1, b2pv1};
#pragma unroll
    for (int p = 0; p < 4; ++p) {
      f32x4 aA = {b1v[2 * p], b1v[2 * p], b1v[2 * p], b1v[2 * p]};
      aA = MFMA16(af.s, W1f[2 * p], aA);
      f32x4 aB = {b1v[2 * p + 1], b1v[2 * p + 1], b1v[2 * p + 1], b1v[2 * p + 1]};
      aB = MFMA16(af.s, W1f[2 * p + 1], aB);
#pragma unroll
      for (int reg = 0; reg < 4; ++reg) {
        lds[wrH + reg * HP] = tanh_fast(aA[reg]);
        lds[wrH + reg * HP + 16] = tanh_fast(aB[reg]);
      }
      S8U hf;
#pragma unroll
      for (int jj = 0; jj < 4; ++jj) {
        float2 v = *(float2*)&lds[rdH + 2 * jj];
        hf.u[jj] = pk2(v.x, v.y);
      }
      u0 = MFMA16(hf.s, W2f[p][0], u0);
      u1 = MFMA16(hf.s, W2f[p][1], u1);
    }

    // ---- integrand s~ (K=40: [x | y]) ----
    f32x4 s0 = {0.f, 0.f, 0.f, 0.f}, s1 = {0.f, 0.f, 0.f, 0.f};
    if (has_s) {
      S8U sf0, sf1;
#pragma unroll
      for (int jj = 0; jj < 4; ++jj) {
        float2 v = *(float2*)&lds[rdXY + 2 * jj];
        sf0.u[jj] = pk2(v.x, v.y);
      }
      if (quad == 0) {
#pragma unroll
        for (int jj = 0; jj < 4; ++jj) {
          float2 v = *(float2*)&lds[rdXY1 + 2 * jj];
          sf1.u[jj] = pk2(v.x, v.y);
        }
      } else {
        sf1.u[0] = sf1.u[1] = sf1.u[2] = sf1.u[3] = 0u;
      }
      f32x4 a0 = {0.f, 0.f, 0.f, 0.f};
      f32x4 a1 = {0.f, 0.f, 0.f, 0.f};
      a0 = MFMA16(sf0.s, Bs[0][0], a0);
      a0 = MFMA16(sf1.s, Bs[1][0], a0);
      a1 = MFMA16(sf0.s, Bs[0][1], a1);
      a1 = MFMA16(sf1.s, Bs[1][1], a1);
      s0 = a0 * dtv;
      s1 = a1 * dtv;
    }

    // ---- scan update ----
    La += s0;
    Lb += s1;
    f32x4 p0 = u0 - La;
    f32x4 p1 = u1 - Lb;
    A2a += p0;
    A2b += p1;
    A1a += p0 * p0;
    A1b += p1 * p1;

    // rotate prefetch
#pragma unroll
    for (int it = 0; it < 5; ++it) {
      xv[it] = xn[it];
      nv[it] = nn[it];
      cv[it] = cn[it];
    }
  }

  // ---- epilogue stores ----
  const size_t CH = (size_t)BATCH * DIM;
  float* zA1 = zc;
  float* zA2 = zc + (size_t)nch * CH;
  float* zS = zc + (size_t)2 * nch * CH;
  const int bb = b0 + quad * 4;
#pragma unroll
  for (int reg = 0; reg < 4; ++reg) {
    size_t base = ((size_t)c * BATCH + (bb + reg)) * 20;
    zA1[base + m16] = A1a[reg];
    zA2[base + m16] = A2a[reg];
    zS[base + m16] = La[reg];
    if (m16 < 4) {
      zA1[base + 16 + m16] = A1b[reg];
      zA2[base + 16 + m16] = A2b[reg];
      zS[base + 16 + m16] = Lb[reg];
    }
  }
}

// ================= kernel B: combine chunks =================
__global__ __launch_bounds__(256) void kB(
    const float* __restrict__ states, const float* __restrict__ lw,
    const float* __restrict__ wsc, const float* __restrict__ zc,
    float* __restrict__ out, int nch, int cbase, int crem) {
  __shared__ float sQp[400];
  int tid = threadIdx.x;
  for (int e = tid; e < 400; e += 256) sQp[e] = wsc[800 + e];
  __syncthreads();
  const int u = blockIdx.x * 256 + tid;  // < 81920
  const int b = u / 20;
  const int i = u - b * 20;
  const float* xp = states + ((size_t)NSTEP * BATCH + b) * 20;
  float term = 0.f;
#pragma unroll
  for (int j = 0; j < 20; ++j) term = fmaf(sQp[i * 20 + j], xp[j], term);

  const size_t CH = (size_t)BATCH * DIM;  // 81920
  float T = 0.f, obj = 0.f;
  for (int c = 0; c < nch; ++c) {
    float A1 = zc[(size_t)c * CH + u];
    float A2 = zc[(size_t)(nch + c) * CH + u];
    float S = zc[(size_t)(2 * nch + c) * CH + u];
    float K = term + T;
    float nc = (float)(cbase + ((c < crem) ? 1 : 0));
    obj += A1 - 2.f * K * A2 + nc * K * K;
    T += S;
  }
  obj *= __expf(lw[b]) * (1.f / ((float)TN * (float)BATCH));
#pragma unroll
  for (int off = 32; off > 0; off >>= 1) obj += __shfl_down(obj, off, 64);
  if ((tid & 63) == 0) atomicAdd(out, obj);
}

extern "C" void kernel_launch(void* const* d_in, const int* in_sizes, int n_in,
                              void* d_out, int out_size, void* d_ws, size_t ws_size,
                              hipStream_t stream) {
  const float* states = (const float*)d_in[0];
  const float* noises = (const float*)d_in[1];
  const float* controls = (const float*)d_in[2];
  const float* lw = (const float*)d_in[3];
  const float* ts = (const float*)d_in[4];
  const float* sigma = (const float*)d_in[5];
  const float* P = (const float*)d_in[6];
  const float* A = (const float*)d_in[7];
  const float* Q = (const float*)d_in[8];
  const float* W1 = (const float*)d_in[9];
  const float* b1 = (const float*)d_in[10];
  const float* W2 = (const float*)d_in[11];
  const float* b2 = (const float*)d_in[12];
  float* out = (float*)d_out;

  float* wsc = (float*)d_ws;
  float* zc = wsc + 8192;

  // choose chunk count by available workspace: nch=16 -> 1024 blocks -> 4 blocks/CU
  int nch = 16;
  size_t need = ((size_t)8192 + (size_t)3 * nch * BATCH * DIM) * sizeof(float);
  if (ws_size < need) nch = 8;
  int cbase = TN / nch;
  int crem = TN - cbase * nch;

  hipMemsetAsync(out, 0, sizeof(float), stream);
  hipLaunchKernelGGL(k0_setup, dim3(1), dim3(256), 0, stream,
                     ts, sigma, A, P, Q, W2, b2, wsc);
  hipLaunchKernelGGL(kA, dim3(nch * 64), dim3(256), 0, stream,
                     states, noises, controls, ts, W1, b1, wsc, zc, nch, cbase, crem);
  hipLaunchKernelGGL(kB, dim3((BATCH * DIM) / 256), dim3(256), 0, stream,
                     states, lw, wsc, zc, out, nch, cbase, crem);
}

// Round 3
// 268.580 us; speedup vs baseline: 1.8020x; 1.1743x over previous
//
#include <hip/hip_runtime.h>
#include <hip/hip_bf16.h>
#include <math.h>

#define TN 201
#define NSTEP 200
#define BATCH 4096
#define DIM 20
#define HID 128

typedef __attribute__((ext_vector_type(8))) short short8;
typedef __attribute__((ext_vector_type(4))) float f32x4;

union S8U { short8 s; unsigned u[4]; };

__device__ __forceinline__ unsigned pk2(float lo, float hi) {
  __hip_bfloat162 h = __float22bfloat162_rn(make_float2(lo, hi));
  union { __hip_bfloat162 h; unsigned u; } v;
  v.h = h;
  return v.u;
}
__device__ __forceinline__ float tanh_fast(float x) {
  float e = __builtin_amdgcn_exp2f(x * 2.8853900817779268f);
  return 1.f - 2.f * __builtin_amdgcn_rcpf(e + 1.f);
}

// ws layout (floats):
//   [0..399]       Pp  = sigma^T P
//   [400..799]     Mp  = -sigma^T A sigma^{-T}
//   [800..1199]    Qp  = sigma^T Q
//   [1200..1399]   dt[200]
//   [1400..1599]   1/sqrt(dt)[200]
//   [1600..1631]   b2p = sigma^T b2 (padded to 32)
//   [2048..4607]   W2p = W2 sigma  [128][20]
//   [5120..7167]   W1F table: 8 frags x 64 lanes x 4 dw (prepacked bf16 pairs)
//   [7168..9215]   W2F table: 8 frags x 64 lanes x 4 dw
//   [9216..10239]  BS  table: 4 frags x 64 lanes x 4 dw
//   [10240..10751] B1  table: [nt 0..7][lane 0..63]
//   [12288 ...]    zc: A1[nch][81920], A2[nch][81920], S[nch][81920]

// ================= k0: setup =================
__global__ __launch_bounds__(256) void k0_setup(
    const float* __restrict__ ts, const float* __restrict__ sigma,
    const float* __restrict__ A, const float* __restrict__ P,
    const float* __restrict__ Q, const float* __restrict__ W2,
    const float* __restrict__ b2, const float* __restrict__ W1,
    const float* __restrict__ b1, float* __restrict__ wsc) {
  __shared__ float aug[20][40];
  __shared__ float sS[400], sA[400], sT1[400];
  __shared__ float fac[20];
  int tid = threadIdx.x;
  for (int e = tid; e < 400; e += 256) { sS[e] = sigma[e]; sA[e] = A[e]; }
  for (int e = tid; e < 800; e += 256) {
    int i = e / 40, j = e % 40;
    aug[i][j] = (j < 20) ? sigma[i * 20 + j] : ((j - 20) == i ? 1.f : 0.f);
  }
  __syncthreads();
  for (int p = 0; p < 20; ++p) {
    // wave 0: scale pivot row + capture fac column (reads before writes,
    // wave-lockstep => safe without extra barrier)
    if (tid < 64) {
      float pv = aug[p][p];
      float r = 1.f / pv;
      float rowv = 0.f, facv = 0.f;
      if (tid < 40) rowv = aug[p][tid];
      if (tid >= 40 && tid < 60) facv = aug[tid - 40][p];
      if (tid < 40) aug[p][tid] = rowv * r;
      if (tid >= 40 && tid < 60) fac[tid - 40] = facv;
    }
    __syncthreads();
    for (int e = tid; e < 800; e += 256) {
      int i = e / 40, j = e % 40;
      if (i != p) aug[i][j] -= fac[i] * aug[p][j];
    }
    __syncthreads();
  }
  // T1[k][j] = (A sigma^{-T})[k][j]
  for (int e = tid; e < 400; e += 256) {
    int k = e / 20, j = e % 20;
    float s = 0.f;
    for (int l2 = 0; l2 < 20; ++l2) s += sA[k * 20 + l2] * aug[j][20 + l2];
    sT1[e] = s;
  }
  __syncthreads();
  for (int e = tid; e < 400; e += 256) {
    int i = e / 20, j = e % 20;
    float m = 0.f, pp = 0.f, qq = 0.f;
    for (int k = 0; k < 20; ++k) {
      float sk = sS[k * 20 + i];
      m += sk * sT1[k * 20 + j];
      pp += sk * P[k * 20 + j];
      qq += sk * Q[k * 20 + j];
    }
    wsc[e] = pp;
    wsc[400 + e] = -m;
    wsc[800 + e] = qq;
  }
  for (int e = tid; e < 2560; e += 256) {
    int h = e / 20, i = e % 20;
    float s = 0.f;
    for (int j = 0; j < 20; ++j) s += W2[h * 20 + j] * sS[j * 20 + i];
    wsc[2048 + e] = s;
  }
  if (tid < 32) {
    float s = 0.f;
    if (tid < 20)
      for (int j = 0; j < 20; ++j) s += b2[j] * sS[j * 20 + tid];
    wsc[1600 + tid] = s;
  }
  if (tid < NSTEP) {
    float d = ts[tid + 1] - ts[tid];
    wsc[1200 + tid] = d;
    wsc[1400 + tid] = rsqrtf(d);
  }
  __syncthreads();  // Pp/Mp/W2p visible before table build

  // ---- prepacked per-lane fragment tables (consumed verbatim by kA) ----
  unsigned* wu = (unsigned*)wsc;
  // W1F: idx = 5120 + nt*256 + l*4 + jj
  for (int e = tid; e < 2048; e += 256) {
    int nt = e >> 8, rem = e & 255, l = rem >> 2, jj = rem & 3;
    int quad = l >> 4, m16 = l & 15;
    int n = nt * 16 + m16;
    int k0 = quad * 8 + 2 * jj;
    float f0 = (k0 < 21) ? W1[k0 * HID + n] : 0.f;
    float f1 = (k0 + 1 < 21) ? W1[(k0 + 1) * HID + n] : 0.f;
    wu[5120 + e] = pk2(f0, f1);
  }
  // W2F: idx = 7168 + (p*2+nt2)*256 + l*4 + jj
  for (int e = tid; e < 2048; e += 256) {
    int pnt = e >> 8, rem = e & 255, l = rem >> 2, jj = rem & 3;
    int p = pnt >> 1, nt2 = pnt & 1;
    int quad = l >> 4, m16 = l & 15;
    int n = nt2 * 16 + m16;
    bool ok = (n < 20);
    int k0 = p * 32 + quad * 8 + 2 * jj;
    float f0 = ok ? wsc[2048 + k0 * 20 + n] : 0.f;
    float f1 = ok ? wsc[2048 + (k0 + 1) * 20 + n] : 0.f;
    wu[7168 + e] = pk2(f0, f1);
  }
  // BS: idx = 9216 + (g*2+nt2)*256 + l*4 + jj
  for (int e = tid; e < 1024; e += 256) {
    int gnt = e >> 8, rem = e & 255, l = rem >> 2, jj = rem & 3;
    int g = gnt >> 1, nt2 = gnt & 1;
    int quad = l >> 4, m16 = l & 15;
    int n = nt2 * 16 + m16;
    bool ok = (n < 20);
    unsigned val = 0u;
    if (g == 0) {
      float v0 = 0.f, v1 = 0.f;
      int k0 = quad * 8 + 2 * jj;
      if (ok) {
        v0 = (k0 < 20) ? wsc[n * 20 + k0] : wsc[400 + n * 20 + (k0 - 20)];
        v1 = (k0 + 1 < 20) ? wsc[n * 20 + k0 + 1] : wsc[400 + n * 20 + (k0 + 1 - 20)];
      }
      val = pk2(v0, v1);
    } else if (ok && quad == 0) {
      val = pk2(wsc[400 + n * 20 + 12 + 2 * jj], wsc[400 + n * 20 + 13 + 2 * jj]);
    }
    wu[9216 + e] = val;
  }
  // B1: idx = 10240 + nt*64 + l -> b1[nt*16 + (l&15)]
  for (int e = tid; e < 512; e += 256) {
    wsc[10240 + e] = b1[(e >> 6) * 16 + (e & 15)];
  }
}

// ================= kernel A: fused MLP + integrand + chunk scan =================
// per-wave LDS rows: tx pitch 26, xy pitch 42, H pitch 34. 1632 dw/wave.
// + 3072 dw block-shared weight tables (W2F 2048 | BS 1024) at float offset 6528.
#define TXP 26
#define XYP 42
#define HP 34
#define WLDS 1632
#define WTF 6528  // = 4*WLDS, float offset of weight tables in LDS

#define MFMA16(a, b, c) __builtin_amdgcn_mfma_f32_16x16x32_bf16((a), (b), (c), 0, 0, 0)

// (256,3): unified VGPR+AGPR budget 170/wave -> 3 waves/SIMD resident.
// (256,4) (budget 128) spilled the weight state to scratch (FETCH 96->720 MB);
// (256,2) (budget 256) let the compiler park ~80 regs of weights in AGPRs,
// silently capping HW occupancy at 2 waves/SIMD. W2f/Bs now live in LDS so
// the live set (~130) fits 170 with slack.
__global__ __launch_bounds__(256, 3) void kA(
    const float* __restrict__ states, const float* __restrict__ noises,
    const float* __restrict__ controls, const float* __restrict__ ts,
    const float* __restrict__ wsc, float* __restrict__ zc,
    int nch, int cbase, int crem) {
  __shared__ __align__(16) float lds[WTF + 3072];
  const int tid = threadIdx.x;
  const int l = tid & 63;
  const int w = tid >> 6;
  const int quad = l >> 4;
  const int m16 = l & 15;

  const int c = blockIdx.x >> 6;    // chunk; c=0 = highest t
  const int slab = blockIdx.x & 63; // 0..63
  const int b0 = slab * 64 + w * 16;
  const int sz = cbase + ((c < crem) ? 1 : 0);
  const int thi = 200 - (c * cbase + ((c < crem) ? c : crem));
  const int tlo = thi - (sz - 1);

  const int twx = w * WLDS;
  const int xyb = twx + 16 * TXP;
  const int hb = xyb + 16 * XYP;

  // ---- zero tx pad cols 21..25 (wave-local region) ----
  for (int e = l; e < 80; e += 64) lds[twx + (e / 5) * TXP + 21 + e % 5] = 0.f;

  // ---- stage W2F+BS tables to LDS (coalesced, block-cooperative) ----
  {
    const float4* src = (const float4*)(wsc + 7168);
    float4* dst = (float4*)(lds + WTF);
    for (int e = tid; e < 768; e += 256) dst[e] = src[e];
  }

  // ---- W1 fragments: 8 coalesced dwordx4 loads from prepacked table ----
  short8 W1f[8];
#pragma unroll
  for (int nt = 0; nt < 8; ++nt)
    W1f[nt] = *(const short8*)(wsc + 5120 + nt * 256 + l * 4);
  float b1v[8];
#pragma unroll
  for (int nt = 0; nt < 8; ++nt) b1v[nt] = wsc[10240 + nt * 64 + l];
  const float b2pv0 = wsc[1600 + m16];
  const float b2pv1 = wsc[1616 + m16];

  // ---- invariant addresses ----
  int srowA[5], srowX[5];
#pragma unroll
  for (int it = 0; it < 5; ++it) {
    int idx = it * 64 + l;
    int row = idx / 20, col = idx - row * 20;
    srowA[it] = twx + row * TXP + 1 + col;
    srowX[it] = xyb + row * XYP + col;
  }
  const int rdTX = twx + m16 * TXP + quad * 8;
  const int rdXY = xyb + m16 * XYP + quad * 8;
  const int rdXY1 = xyb + m16 * XYP + 32;
  const int wrH = hb + quad * 4 * HP + m16;
  const int rdH = hb + m16 * HP + quad * 8;
  const int wtl = WTF + l * 4;  // per-lane base into weight tables

  // ---- scan accumulators ----
  f32x4 A1a = {0.f, 0.f, 0.f, 0.f}, A1b = {0.f, 0.f, 0.f, 0.f};
  f32x4 A2a = {0.f, 0.f, 0.f, 0.f}, A2b = {0.f, 0.f, 0.f, 0.f};
  f32x4 La = {0.f, 0.f, 0.f, 0.f}, Lb = {0.f, 0.f, 0.f, 0.f};

  // ---- preload first t ----
  float xv[5], nv[5], cv[5];
  {
    size_t rb = ((size_t)thi * BATCH + b0) * 20;
#pragma unroll
    for (int it = 0; it < 5; ++it) {
      int idx = it * 64 + l;
      xv[it] = states[rb + idx];
      if (thi < 200) {
        nv[it] = noises[rb + idx];
        cv[it] = controls[rb + idx];
      }
    }
  }

  __syncthreads();  // weight tables visible to all waves

#pragma unroll 1
  for (int t = thi; t >= tlo; --t) {
    float xn[5], nn[5], cn[5];
    if (t > tlo) {
      size_t rb = ((size_t)(t - 1) * BATCH + b0) * 20;
#pragma unroll
      for (int it = 0; it < 5; ++it) {
        int idx = it * 64 + l;
        xn[it] = states[rb + idx];
        nn[it] = noises[rb + idx];
        cn[it] = controls[rb + idx];
      }
    }
    const float tval = ts[t];
    const bool has_s = (t < 200);
    const float dtv = has_s ? wsc[1200 + t] : 0.f;
    const float rsd = has_s ? wsc[1400 + t] : 0.f;

    // ---- stage rows to LDS (wave-local) ----
#pragma unroll
    for (int it = 0; it < 5; ++it) {
      lds[srowA[it]] = xv[it];
      lds[srowX[it]] = xv[it];
      if (has_s) lds[srowX[it] + 20] = nv[it] * rsd + cv[it];
    }
    if (l < 16) lds[twx + l * TXP] = tval;

    // ---- XA fragment ----
    S8U af;
    if (quad < 3) {
#pragma unroll
      for (int jj = 0; jj < 4; ++jj) {
        float2 v = *(float2*)&lds[rdTX + 2 * jj];
        af.u[jj] = pk2(v.x, v.y);
      }
    } else {
      af.u[0] = af.u[1] = af.u[2] = af.u[3] = 0u;
    }

    // ---- MLP: layer1 -> tanh -> layer2 (W2 frags from LDS) ----
    f32x4 u0 = {b2pv0, b2pv0, b2pv0, b2pv0};
    f32x4 u1 = {b2pv1, b2pv1, b2pv1, b2pv1};
#pragma unroll
    for (int p = 0; p < 4; ++p) {
      f32x4 aA = {b1v[2 * p], b1v[2 * p], b1v[2 * p], b1v[2 * p]};
      aA = MFMA16(af.s, W1f[2 * p], aA);
      f32x4 aB = {b1v[2 * p + 1], b1v[2 * p + 1], b1v[2 * p + 1], b1v[2 * p + 1]};
      aB = MFMA16(af.s, W1f[2 * p + 1], aB);
#pragma unroll
      for (int reg = 0; reg < 4; ++reg) {
        lds[wrH + reg * HP] = tanh_fast(aA[reg]);
        lds[wrH + reg * HP + 16] = tanh_fast(aB[reg]);
      }
      S8U hf;
#pragma unroll
      for (int jj = 0; jj < 4; ++jj) {
        float2 v = *(float2*)&lds[rdH + 2 * jj];
        hf.u[jj] = pk2(v.x, v.y);
      }
      u0 = MFMA16(hf.s, *(const short8*)&lds[wtl + (p * 2 + 0) * 256], u0);
      u1 = MFMA16(hf.s, *(const short8*)&lds[wtl + (p * 2 + 1) * 256], u1);
    }

    // ---- integrand s~ (K=40: [x | y], B frags from LDS) ----
    f32x4 s0 = {0.f, 0.f, 0.f, 0.f}, s1 = {0.f, 0.f, 0.f, 0.f};
    if (has_s) {
      S8U sf0, sf1;
#pragma unroll
      for (int jj = 0; jj < 4; ++jj) {
        float2 v = *(float2*)&lds[rdXY + 2 * jj];
        sf0.u[jj] = pk2(v.x, v.y);
      }
      if (quad == 0) {
#pragma unroll
        for (int jj = 0; jj < 4; ++jj) {
          float2 v = *(float2*)&lds[rdXY1 + 2 * jj];
          sf1.u[jj] = pk2(v.x, v.y);
        }
      } else {
        sf1.u[0] = sf1.u[1] = sf1.u[2] = sf1.u[3] = 0u;
      }
      f32x4 a0 = {0.f, 0.f, 0.f, 0.f};
      f32x4 a1 = {0.f, 0.f, 0.f, 0.f};
      a0 = MFMA16(sf0.s, *(const short8*)&lds[wtl + 2048 + 0 * 256], a0);
      a0 = MFMA16(sf1.s, *(const short8*)&lds[wtl + 2048 + 2 * 256], a0);
      a1 = MFMA16(sf0.s, *(const short8*)&lds[wtl + 2048 + 1 * 256], a1);
      a1 = MFMA16(sf1.s, *(const short8*)&lds[wtl + 2048 + 3 * 256], a1);
      s0 = a0 * dtv;
      s1 = a1 * dtv;
    }

    // ---- scan update ----
    La += s0;
    Lb += s1;
    f32x4 p0 = u0 - La;
    f32x4 p1 = u1 - Lb;
    A2a += p0;
    A2b += p1;
    A1a += p0 * p0;
    A1b += p1 * p1;

#pragma unroll
    for (int it = 0; it < 5; ++it) {
      xv[it] = xn[it];
      nv[it] = nn[it];
      cv[it] = cn[it];
    }
  }

  // ---- epilogue stores ----
  const size_t CH = (size_t)BATCH * DIM;
  float* zA1 = zc;
  float* zA2 = zc + (size_t)nch * CH;
  float* zS = zc + (size_t)2 * nch * CH;
  const int bb = b0 + quad * 4;
#pragma unroll
  for (int reg = 0; reg < 4; ++reg) {
    size_t base = ((size_t)c * BATCH + (bb + reg)) * 20;
    zA1[base + m16] = A1a[reg];
    zA2[base + m16] = A2a[reg];
    zS[base + m16] = La[reg];
    if (m16 < 4) {
      zA1[base + 16 + m16] = A1b[reg];
      zA2[base + 16 + m16] = A2b[reg];
      zS[base + 16 + m16] = Lb[reg];
    }
  }
}

// ================= kernel B: combine chunks =================
__global__ __launch_bounds__(256) void kB(
    const float* __restrict__ states, const float* __restrict__ lw,
    const float* __restrict__ wsc, const float* __restrict__ zc,
    float* __restrict__ out, int nch, int cbase, int crem) {
  __shared__ float sQp[400];
  __shared__ float part[4];
  int tid = threadIdx.x;
  for (int e = tid; e < 400; e += 256) sQp[e] = wsc[800 + e];
  __syncthreads();
  const int u = blockIdx.x * 256 + tid;  // < 81920
  const int b = u / 20;
  const int i = u - b * 20;
  const float* xp = states + ((size_t)NSTEP * BATCH + b) * 20;
  float term = 0.f;
#pragma unroll
  for (int j = 0; j < 20; ++j) term = fmaf(sQp[i * 20 + j], xp[j], term);

  const size_t CH = (size_t)BATCH * DIM;  // 81920
  float T = 0.f, obj = 0.f;
  for (int c = 0; c < nch; ++c) {
    float A1 = zc[(size_t)c * CH + u];
    float A2 = zc[(size_t)(nch + c) * CH + u];
    float S = zc[(size_t)(2 * nch + c) * CH + u];
    float K = term + T;
    float nc = (float)(cbase + ((c < crem) ? 1 : 0));
    obj += A1 - 2.f * K * A2 + nc * K * K;
    T += S;
  }
  obj *= __expf(lw[b]) * (1.f / ((float)TN * (float)BATCH));
#pragma unroll
  for (int off = 32; off > 0; off >>= 1) obj += __shfl_down(obj, off, 64);
  if ((tid & 63) == 0) part[tid >> 6] = obj;
  __syncthreads();
  if (tid == 0) atomicAdd(out, (part[0] + part[1]) + (part[2] + part[3]));
}

extern "C" void kernel_launch(void* const* d_in, const int* in_sizes, int n_in,
                              void* d_out, int out_size, void* d_ws, size_t ws_size,
                              hipStream_t stream) {
  const float* states = (const float*)d_in[0];
  const float* noises = (const float*)d_in[1];
  const float* controls = (const float*)d_in[2];
  const float* lw = (const float*)d_in[3];
  const float* ts = (const float*)d_in[4];
  const float* sigma = (const float*)d_in[5];
  const float* P = (const float*)d_in[6];
  const float* A = (const float*)d_in[7];
  const float* Q = (const float*)d_in[8];
  const float* W1 = (const float*)d_in[9];
  const float* b1 = (const float*)d_in[10];
  const float* W2 = (const float*)d_in[11];
  const float* b2 = (const float*)d_in[12];
  float* out = (float*)d_out;

  float* wsc = (float*)d_ws;
  float* zc = wsc + 12288;

  // nch=12 -> 768 blocks = 3 blocks/CU (matches 3 waves/SIMD reg budget)
  int nch = 12;
  size_t need = ((size_t)12288 + (size_t)3 * nch * BATCH * DIM) * sizeof(float);
  if (ws_size < need) nch = 8;
  int cbase = TN / nch;
  int crem = TN - cbase * nch;

  hipMemsetAsync(out, 0, sizeof(float), stream);
  hipLaunchKernelGGL(k0_setup, dim3(1), dim3(256), 0, stream,
                     ts, sigma, A, P, Q, W2, b2, W1, b1, wsc);
  hipLaunchKernelGGL(kA, dim3(nch * 64), dim3(256), 0, stream,
                     states, noises, controls, ts, wsc, zc, nch, cbase, crem);
  hipLaunchKernelGGL(kB, dim3((BATCH * DIM) / 256), dim3(256), 0, stream,
                     states, lw, wsc, zc, out, nch, cbase, crem);
}